// Round 1
// baseline (746.779 us; speedup 1.0000x reference)
//
#include <hip/hip_runtime.h>
#include <hip/hip_bf16.h>
#include <cstdint>

// SemlaLayer fused forward for MI355X (gfx950).
// B=4, N=256, D_EQUI=64, D_INV=256, D_MSG=64, N_HEADS=8, D_FF=256,
// D_EDGE_IN=64, D_EDGE_OUT=64, IN_FEATS=256, D_OUT=136.

typedef __bf16 bf16x4_t __attribute__((ext_vector_type(4)));
typedef __bf16 bf16x8_t __attribute__((ext_vector_type(8)));
typedef float  f32x4_t  __attribute__((ext_vector_type(4)));

#define SP 76  // sS pitch in floats (64 equi + 8 inv cols, padded vs bank aliasing)

__device__ __forceinline__ int swz(int row, int col) {
    // element-index XOR swizzle at 8-element (16B) granularity: kills the
    // 16-way bank conflict of stride-512B ds_read_b128 column reads (G4).
    return (row << 8) + (col ^ ((row & 7) << 3));
}

__device__ __forceinline__ bf16x4_t cvt4(float4 v) {
    bf16x4_t r;
    r[0] = (__bf16)v.x; r[1] = (__bf16)v.y; r[2] = (__bf16)v.z; r[3] = (__bf16)v.w;
    return r;
}

// ---------------- pre-kernel: projections + weight conversion ----------------
// blocks [0,128): 8 (b,n) rows each -> qmsg,kmsg,projE,projF
// blocks [128,144): W1 fp32->bf16   blocks [144,153): W2 fp32->bf16 (pad 136->144)
__global__ __launch_bounds__(256) void semla_pre(
    const float* __restrict__ invs, const float* __restrict__ equis,
    const float* __restrict__ Wq, const float* __restrict__ bq,
    const float* __restrict__ Wk, const float* __restrict__ bk,
    const float* __restrict__ Wc, const float* __restrict__ Wi, const float* __restrict__ bi,
    const float* __restrict__ W1, const float* __restrict__ W2,
    __bf16* __restrict__ W1bf, __bf16* __restrict__ W2bf,
    float* __restrict__ qmsg, float* __restrict__ kmsg,
    float* __restrict__ projE, float* __restrict__ projF)
{
    const int blk = blockIdx.x, tid = threadIdx.x;
    if (blk < 128) {
        const int r0 = blk * 8;
        __shared__ __align__(16) float sInv8[8][256];
        __shared__ __align__(16) float sEqu8[8][192];
        #pragma unroll
        for (int j = 0; j < 8; ++j) {
            sInv8[j][tid] = invs[(size_t)(r0 + j) * 256 + tid];
            if (tid < 192) sEqu8[j][tid] = equis[(size_t)(r0 + j) * 192 + tid];
        }
        __syncthreads();
        // projF = invs @ Wi.T + bi   (thread = output o, 8 rows batched)
        {
            float acc[8] = {0.f,0.f,0.f,0.f,0.f,0.f,0.f,0.f};
            const float* w = &Wi[tid * 256];
            for (int i = 0; i < 256; i += 4) {
                float4 ww = *(const float4*)&w[i];
                #pragma unroll
                for (int j = 0; j < 8; ++j) {
                    const float* x = &sInv8[j][i];
                    acc[j] += ww.x * x[0] + ww.y * x[1] + ww.z * x[2] + ww.w * x[3];
                }
            }
            const float bb = bi[tid];
            #pragma unroll
            for (int j = 0; j < 8; ++j) projF[(size_t)(r0 + j) * 256 + tid] = acc[j] + bb;
        }
        // qmsg / kmsg
        if (tid < 128) {
            const int d = tid & 63;
            const float* w = (tid < 64) ? &Wq[d * 256] : &Wk[d * 256];
            float acc[8] = {0.f,0.f,0.f,0.f,0.f,0.f,0.f,0.f};
            for (int i = 0; i < 256; i += 4) {
                float4 ww = *(const float4*)&w[i];
                #pragma unroll
                for (int j = 0; j < 8; ++j) {
                    const float* x = &sInv8[j][i];
                    acc[j] += ww.x * x[0] + ww.y * x[1] + ww.z * x[2] + ww.w * x[3];
                }
            }
            const float bb = (tid < 64) ? bq[d] : bk[d];
            float* dst = (tid < 64) ? qmsg : kmsg;
            #pragma unroll
            for (int j = 0; j < 8; ++j) dst[(size_t)(r0 + j) * 64 + d] = acc[j] + bb;
        }
        // projE = equis @ Wc.T   (thread = (c,e))
        if (tid < 192) {
            const int c = tid >> 6, e = tid & 63;
            const float* w = &Wc[e * 64];
            float acc[8] = {0.f,0.f,0.f,0.f,0.f,0.f,0.f,0.f};
            for (int dd = 0; dd < 64; dd += 4) {
                float4 ww = *(const float4*)&w[dd];
                #pragma unroll
                for (int j = 0; j < 8; ++j) {
                    const float* x = &sEqu8[j][c * 64 + dd];
                    acc[j] += ww.x * x[0] + ww.y * x[1] + ww.z * x[2] + ww.w * x[3];
                }
            }
            #pragma unroll
            for (int j = 0; j < 8; ++j) projE[(size_t)(r0 + j) * 192 + tid] = acc[j];
        }
    } else if (blk < 144) {
        const int base = (blk - 128) * 4096;
        #pragma unroll
        for (int r = 0; r < 16; ++r) {
            const int idx = base + r * 256 + tid;
            W1bf[idx] = (__bf16)W1[idx];
        }
    } else if (blk < 153) {
        const int base = (blk - 144) * 4096;
        #pragma unroll
        for (int r = 0; r < 16; ++r) {
            const int idx = base + r * 256 + tid;     // idx < 144*256
            const int o = idx >> 8, cc = idx & 255;
            W2bf[idx] = (__bf16)((o < 136) ? W2[o * 256 + cc] : 0.f);
        }
    }
}

// ---------------- main fused kernel: one workgroup per (b,q) ----------------
__global__ __launch_bounds__(256, 2) void semla_main(
    const float* __restrict__ equis, const float* __restrict__ edges,
    const int* __restrict__ adj,
    const __bf16* __restrict__ W1bf, const __bf16* __restrict__ W2bf,
    const float* __restrict__ qmsg, const float* __restrict__ kmsg,
    const float* __restrict__ projE, const float* __restrict__ projF,
    const float* __restrict__ b1, const float* __restrict__ b2,
    const float* __restrict__ Wa, const float* __restrict__ Wo,
    const float* __restrict__ bo,
    float* __restrict__ outE, float* __restrict__ outI, float* __restrict__ outEdge)
{
    const int bqid = blockIdx.x;          // b*256 + q
    const int b = bqid >> 8;
    const int tid = threadIdx.x;
    const int wave = tid >> 6, lane = tid & 63;
    const int arow = lane & 15, kgrp = lane >> 4;

    __shared__ __align__(16) __bf16 sX[64 * 256];   // 32KB: X tile, then H tile
    __shared__ __align__(16) float  sS[64 * SP];    // logits -> p; reused at finalize
    __shared__ __align__(16) float  sB1[256];
    __shared__ __align__(16) float  sB2[144];
    __shared__ __align__(16) float  sEquiQ[192];
    __shared__ __align__(16) __bf16 sQm[64];
    __shared__ float sF[72];
    __shared__ float sL[72];
    __shared__ float sL2[72];
    __shared__ int   sAdj[64];

    sB1[tid] = b1[tid];
    if (tid < 144) sB2[tid] = (tid < 136) ? b2[tid] : 0.f;
    if (tid < 192) sEquiQ[tid] = equis[(size_t)bqid * 192 + tid];
    if (tid < 64)  sQm[tid] = (__bf16)qmsg[(size_t)bqid * 64 + tid];

    // per-thread persistent attention state
    float m_run = -1e30f, l_run = 0.f, l2_run = 0.f;
    float accE = 0.f;                       // role (c,d) for tid<192
    float accI = 0.f;                       // role (h,dd) = (tid>>5, tid&31)
    const int c_e = tid >> 6, d_e = tid & 63;
    const int h_i = tid >> 5;
    __syncthreads();

    for (int kt = 0; kt < 4; ++kt) {
        const int k0 = kt * 64;
        const int kb = b * 256 + k0;

        // ---- build X tile: [64 k-rows][qmsg|kmsg|dot|edges] bf16 ----
        #pragma unroll
        for (int it = 0; it < 4; ++it) {
            const int i = tid + it * 256;
            const int r = i >> 4, c4 = (i & 15) << 2;
            *(bf16x4_t*)&sX[swz(r, c4)] = *(const bf16x4_t*)&sQm[c4];
        }
        #pragma unroll
        for (int it = 0; it < 4; ++it) {
            const int i = tid + it * 256;
            const int r = i >> 4, c4 = (i & 15) << 2;
            float4 v = *(const float4*)&kmsg[(size_t)(kb + r) * 64 + c4];
            *(bf16x4_t*)&sX[swz(r, 64 + c4)] = cvt4(v);
        }
        #pragma unroll
        for (int it = 0; it < 4; ++it) {
            const int i = tid + it * 256;
            const int r = i >> 4, c4 = (i & 15) << 2;
            const float* ek = &equis[(size_t)(kb + r) * 192 + c4];
            float4 e0 = *(const float4*)(ek);
            float4 e1 = *(const float4*)(ek + 64);
            float4 e2 = *(const float4*)(ek + 128);
            float4 q0 = *(const float4*)&sEquiQ[c4];
            float4 q1 = *(const float4*)&sEquiQ[64 + c4];
            float4 q2 = *(const float4*)&sEquiQ[128 + c4];
            float4 d;
            d.x = e0.x * q0.x + e1.x * q1.x + e2.x * q2.x;
            d.y = e0.y * q0.y + e1.y * q1.y + e2.y * q2.y;
            d.z = e0.z * q0.z + e1.z * q1.z + e2.z * q2.z;
            d.w = e0.w * q0.w + e1.w * q1.w + e2.w * q2.w;
            *(bf16x4_t*)&sX[swz(r, 128 + c4)] = cvt4(d);
        }
        #pragma unroll
        for (int it = 0; it < 4; ++it) {
            const int i = tid + it * 256;
            const int r = i >> 4, c4 = (i & 15) << 2;
            float4 v = *(const float4*)&edges[((size_t)bqid * 256 + k0 + r) * 64 + c4];
            *(bf16x4_t*)&sX[swz(r, 192 + c4)] = cvt4(v);
        }
        if (tid < 64) sAdj[tid] = adj[(size_t)bqid * 256 + k0 + tid];
        __syncthreads();

        // ---- GEMM1: H = silu(X @ W1^T + b1), wave owns 64 FF cols ----
        f32x4_t acc1[4][4];
        {
            const f32x4_t z = {0.f, 0.f, 0.f, 0.f};
            #pragma unroll
            for (int rt = 0; rt < 4; ++rt)
                #pragma unroll
                for (int ct = 0; ct < 4; ++ct) acc1[rt][ct] = z;
        }
        #pragma unroll
        for (int ks = 0; ks < 8; ++ks) {
            const int kk = ks * 32 + (kgrp << 3);
            bf16x8_t afr[4], bfr[4];
            #pragma unroll
            for (int rt = 0; rt < 4; ++rt)
                afr[rt] = *(const bf16x8_t*)&sX[swz((rt << 4) + arow, kk)];
            #pragma unroll
            for (int ct = 0; ct < 4; ++ct) {
                const int o = (wave << 6) + (ct << 4) + arow;
                bfr[ct] = *(const bf16x8_t*)&W1bf[(o << 8) + kk];
            }
            #pragma unroll
            for (int rt = 0; rt < 4; ++rt)
                #pragma unroll
                for (int ct = 0; ct < 4; ++ct)
                    acc1[rt][ct] = __builtin_amdgcn_mfma_f32_16x16x32_bf16(
                        afr[rt], bfr[ct], acc1[rt][ct], 0, 0, 0);
        }
        __syncthreads();                      // all waves done reading X
        #pragma unroll
        for (int rt = 0; rt < 4; ++rt)
            #pragma unroll
            for (int ct = 0; ct < 4; ++ct) {
                const int ccol = (wave << 6) + (ct << 4) + arow;
                const float bb = sB1[ccol];
                #pragma unroll
                for (int j = 0; j < 4; ++j) {
                    const int row = (rt << 4) + (kgrp << 2) + j;
                    float x = acc1[rt][ct][j] + bb;
                    float hh = x * (1.0f / (1.0f + __expf(-x)));
                    sX[swz(row, ccol)] = (__bf16)hh;
                }
            }
        __syncthreads();                      // H ready

        // ---- GEMM2: messages = H @ W2^T + b2 (N padded 136->144) ----
        const int ct0 = wave ? (2 * wave + 1) : 0;   // 0,3,5,7
        const int nct = wave ? 2 : 3;
        f32x4_t acc2[4][3];
        {
            const f32x4_t z = {0.f, 0.f, 0.f, 0.f};
            #pragma unroll
            for (int rt = 0; rt < 4; ++rt)
                #pragma unroll
                for (int ci = 0; ci < 3; ++ci) acc2[rt][ci] = z;
        }
        #pragma unroll
        for (int ks = 0; ks < 8; ++ks) {
            const int kk = ks * 32 + (kgrp << 3);
            bf16x8_t afr[4], bfr[3];
            #pragma unroll
            for (int rt = 0; rt < 4; ++rt)
                afr[rt] = *(const bf16x8_t*)&sX[swz((rt << 4) + arow, kk)];
            #pragma unroll
            for (int ci = 0; ci < 3; ++ci)
                if (ci < nct) {
                    const int o = ((ct0 + ci) << 4) + arow;
                    bfr[ci] = *(const bf16x8_t*)&W2bf[(o << 8) + kk];
                }
            #pragma unroll
            for (int rt = 0; rt < 4; ++rt)
                #pragma unroll
                for (int ci = 0; ci < 3; ++ci)
                    if (ci < nct)
                        acc2[rt][ci] = __builtin_amdgcn_mfma_f32_16x16x32_bf16(
                            afr[rt], bfr[ci], acc2[rt][ci], 0, 0, 0);
        }
        // epilogue: logits (ch<72) -> sS, edge channels -> global
        #pragma unroll
        for (int ci = 0; ci < 3; ++ci)
            if (ci < nct) {
                const int ch = ((ct0 + ci) << 4) + arow;
                const float bb = sB2[ch];
                #pragma unroll
                for (int rt = 0; rt < 4; ++rt)
                    #pragma unroll
                    for (int j = 0; j < 4; ++j) {
                        const int r = (rt << 4) + (kgrp << 2) + j;
                        const float v = acc2[rt][ci][j] + bb;
                        if (ch < 72) sS[r * SP + ch] = v;
                        else if (ch < 136)
                            outEdge[((size_t)bqid * 256 + k0 + r) * 64 + (ch - 72)] = v;
                    }
            }
        __syncthreads();                      // logits + adj ready

        // ---- pass A: per-channel online softmax (masked skip == exact ref) ----
        if (tid < 72) {
            float tm = -1e30f;
            #pragma unroll 4
            for (int k = 0; k < 64; ++k)
                if (sAdj[k]) tm = fmaxf(tm, sS[k * SP + tid]);
            const float mN = fmaxf(m_run, tm);
            const float f = __expf(m_run - mN);
            float s1 = 0.f, s2 = 0.f;
            #pragma unroll 4
            for (int k = 0; k < 64; ++k) {
                float p = sAdj[k] ? __expf(sS[k * SP + tid] - mN) : 0.f;
                sS[k * SP + tid] = p;
                s1 += p; s2 += p * p;
            }
            l_run = l_run * f + s1;
            l2_run = l2_run * f * f + s2;
            m_run = mN;
            sF[tid] = f;
        }
        __syncthreads();                      // p + rescale factors ready

        // ---- pass B: accumulate attention outputs ----
        if (tid < 192) {
            float a = accE * sF[d_e];
            const float* pe = &projE[((size_t)kb * 3 + c_e) * 64 + d_e];
            #pragma unroll 4
            for (int k = 0; k < 64; ++k)
                a += sS[k * SP + d_e] * pe[k * 192];
            accE = a;
        }
        {
            float a = accI * sF[64 + h_i];
            const float* pf = &projF[(size_t)kb * 256 + tid];
            #pragma unroll 4
            for (int k = 0; k < 64; ++k)
                a += sS[k * SP + 64 + h_i] * pf[k * 256];
            accI = a;
        }
        // no barrier needed: next writes to sS/sF occur after >=1 barrier
    }

    // ---- finalize ----
    if (tid < 72) { sL[tid] = l_run; sL2[tid] = l2_run; }
    __syncthreads();                          // also fences last pass-B sS reads
    if (tid < 192) {
        const float ll = sL[d_e];
        sS[tid] = accE * sqrtf(sL2[d_e]) / (ll * ll);            // out_e[c][d]
    }
    {
        const float ll = sL[64 + h_i];
        sS[256 + tid] = accI * sqrtf(sL2[64 + h_i]) / (ll * ll); // out_i flat
    }
    __syncthreads();
    if (tid < 192) {                          // equi_updates = out_e @ Wa^T
        const int c = tid >> 6, e = tid & 63;
        float s = 0.f;
        #pragma unroll 8
        for (int d2 = 0; d2 < 64; ++d2) s += sS[c * 64 + d2] * Wa[e * 64 + d2];
        outE[((size_t)bqid * 3 + c) * 64 + e] = s;
    }
    {                                         // inv_updates = out_i @ Wo^T + bo
        float s = 0.f;
        const float* wo = &Wo[tid * 256];
        #pragma unroll 8
        for (int i = 0; i < 256; ++i) s += sS[256 + i] * wo[i];
        outI[(size_t)bqid * 256 + tid] = s + bo[tid];
    }
}

extern "C" void kernel_launch(void* const* d_in, const int* in_sizes, int n_in,
                              void* d_out, int out_size, void* d_ws, size_t ws_size,
                              hipStream_t stream) {
    (void)in_sizes; (void)n_in; (void)out_size; (void)ws_size;
    const float* equis = (const float*)d_in[0];
    const float* invs  = (const float*)d_in[1];
    const float* edges = (const float*)d_in[2];
    const int*   adj   = (const int*)d_in[3];
    const float* Wq = (const float*)d_in[4];
    const float* bq = (const float*)d_in[5];
    const float* Wk = (const float*)d_in[6];
    const float* bk = (const float*)d_in[7];
    const float* W1 = (const float*)d_in[8];
    const float* b1 = (const float*)d_in[9];
    const float* W2 = (const float*)d_in[10];
    const float* b2 = (const float*)d_in[11];
    const float* Wc = (const float*)d_in[12];
    const float* Wa = (const float*)d_in[13];
    const float* Wi = (const float*)d_in[14];
    const float* bi = (const float*)d_in[15];
    const float* Wo = (const float*)d_in[16];
    const float* bo = (const float*)d_in[17];

    float* out = (float*)d_out;
    float* outE    = out;                  // (B,N,3,64)  = 196608
    float* outI    = out + 196608;         // (B,N,256)   = 262144
    float* outEdge = out + 458752;         // (B,N,N,64)  = 16777216

    char* ws = (char*)d_ws;
    __bf16* W1bf = (__bf16*)(ws);                    // 131072 B
    __bf16* W2bf = (__bf16*)(ws + 131072);           //  73728 B
    float* qmsg  = (float*)(ws + 204800);            // 262144 B
    float* kmsg  = (float*)(ws + 466944);            // 262144 B
    float* projE = (float*)(ws + 729088);            // 786432 B
    float* projF = (float*)(ws + 1515520);           // 1048576 B

    semla_pre<<<153, 256, 0, stream>>>(invs, equis, Wq, bq, Wk, bk, Wc, Wi, bi,
                                       W1, W2, W1bf, W2bf, qmsg, kmsg, projE, projF);
    semla_main<<<1024, 256, 0, stream>>>(equis, edges, adj, W1bf, W2bf, qmsg, kmsg,
                                         projE, projF, b1, b2, Wa, Wo, bo,
                                         outE, outI, outEdge);
}

// Round 3
// 695.100 us; speedup vs baseline: 1.0743x; 1.0743x over previous
//
#include <hip/hip_runtime.h>
#include <hip/hip_bf16.h>
#include <cstdint>

// SemlaLayer fused forward for MI355X (gfx950).
// B=4, N=256, D_EQUI=64, D_INV=256, D_MSG=64, N_HEADS=8, D_FF=256,
// D_EDGE_IN=64, D_EDGE_OUT=64, IN_FEATS=256, D_OUT=136.
// R1/R2 changes: KV tile 64->32 (LDS 56->39KB => 4 blocks/CU), edge_out staged
// in LDS + coalesced nontemporal row flush, nontemporal edges loads
// (via ext_vector float4 type accepted by the builtin).

typedef __bf16 bf16x4_t __attribute__((ext_vector_type(4)));
typedef __bf16 bf16x8_t __attribute__((ext_vector_type(8)));
typedef float  f32x4_t  __attribute__((ext_vector_type(4)));

#define SP 76   // sS pitch in floats
#define KV 32   // k-tile rows

__device__ __forceinline__ int swz(int row, int col) {
    // element-index XOR swizzle at 8-element (16B) granularity (G4).
    return (row << 8) + (col ^ ((row & 7) << 3));
}

__device__ __forceinline__ bf16x4_t cvt4(f32x4_t v) {
    bf16x4_t r;
    r[0] = (__bf16)v.x; r[1] = (__bf16)v.y; r[2] = (__bf16)v.z; r[3] = (__bf16)v.w;
    return r;
}

// ---------------- pre-kernel: projections + weight conversion ----------------
__global__ __launch_bounds__(256) void semla_pre(
    const float* __restrict__ invs, const float* __restrict__ equis,
    const float* __restrict__ Wq, const float* __restrict__ bq,
    const float* __restrict__ Wk, const float* __restrict__ bk,
    const float* __restrict__ Wc, const float* __restrict__ Wi, const float* __restrict__ bi,
    const float* __restrict__ W1, const float* __restrict__ W2,
    __bf16* __restrict__ W1bf, __bf16* __restrict__ W2bf,
    float* __restrict__ qmsg, float* __restrict__ kmsg,
    float* __restrict__ projE, float* __restrict__ projF)
{
    const int blk = blockIdx.x, tid = threadIdx.x;
    if (blk < 128) {
        const int r0 = blk * 8;
        __shared__ __align__(16) float sInv8[8][256];
        __shared__ __align__(16) float sEqu8[8][192];
        #pragma unroll
        for (int j = 0; j < 8; ++j) {
            sInv8[j][tid] = invs[(size_t)(r0 + j) * 256 + tid];
            if (tid < 192) sEqu8[j][tid] = equis[(size_t)(r0 + j) * 192 + tid];
        }
        __syncthreads();
        {
            float acc[8] = {0.f,0.f,0.f,0.f,0.f,0.f,0.f,0.f};
            const float* w = &Wi[tid * 256];
            for (int i = 0; i < 256; i += 4) {
                f32x4_t ww = *(const f32x4_t*)&w[i];
                #pragma unroll
                for (int j = 0; j < 8; ++j) {
                    const float* x = &sInv8[j][i];
                    acc[j] += ww.x * x[0] + ww.y * x[1] + ww.z * x[2] + ww.w * x[3];
                }
            }
            const float bb = bi[tid];
            #pragma unroll
            for (int j = 0; j < 8; ++j) projF[(size_t)(r0 + j) * 256 + tid] = acc[j] + bb;
        }
        if (tid < 128) {
            const int d = tid & 63;
            const float* w = (tid < 64) ? &Wq[d * 256] : &Wk[d * 256];
            float acc[8] = {0.f,0.f,0.f,0.f,0.f,0.f,0.f,0.f};
            for (int i = 0; i < 256; i += 4) {
                f32x4_t ww = *(const f32x4_t*)&w[i];
                #pragma unroll
                for (int j = 0; j < 8; ++j) {
                    const float* x = &sInv8[j][i];
                    acc[j] += ww.x * x[0] + ww.y * x[1] + ww.z * x[2] + ww.w * x[3];
                }
            }
            const float bb = (tid < 64) ? bq[d] : bk[d];
            float* dst = (tid < 64) ? qmsg : kmsg;
            #pragma unroll
            for (int j = 0; j < 8; ++j) dst[(size_t)(r0 + j) * 64 + d] = acc[j] + bb;
        }
        if (tid < 192) {
            const int c = tid >> 6, e = tid & 63;
            const float* w = &Wc[e * 64];
            float acc[8] = {0.f,0.f,0.f,0.f,0.f,0.f,0.f,0.f};
            for (int dd = 0; dd < 64; dd += 4) {
                f32x4_t ww = *(const f32x4_t*)&w[dd];
                #pragma unroll
                for (int j = 0; j < 8; ++j) {
                    const float* x = &sEqu8[j][c * 64 + dd];
                    acc[j] += ww.x * x[0] + ww.y * x[1] + ww.z * x[2] + ww.w * x[3];
                }
            }
            #pragma unroll
            for (int j = 0; j < 8; ++j) projE[(size_t)(r0 + j) * 192 + tid] = acc[j];
        }
    } else if (blk < 144) {
        const int base = (blk - 128) * 4096;
        #pragma unroll
        for (int r = 0; r < 16; ++r) {
            const int idx = base + r * 256 + tid;
            W1bf[idx] = (__bf16)W1[idx];
        }
    } else if (blk < 153) {
        const int base = (blk - 144) * 4096;
        #pragma unroll
        for (int r = 0; r < 16; ++r) {
            const int idx = base + r * 256 + tid;     // idx < 144*256
            const int o = idx >> 8, cc = idx & 255;
            W2bf[idx] = (__bf16)((o < 136) ? W2[o * 256 + cc] : 0.f);
        }
    }
}

// ---------------- main fused kernel: one workgroup per (b,q) ----------------
__global__ __launch_bounds__(256, 4) void semla_main(
    const float* __restrict__ equis, const float* __restrict__ edges,
    const int* __restrict__ adj,
    const __bf16* __restrict__ W1bf, const __bf16* __restrict__ W2bf,
    const float* __restrict__ qmsg, const float* __restrict__ kmsg,
    const float* __restrict__ projE, const float* __restrict__ projF,
    const float* __restrict__ b1, const float* __restrict__ b2,
    const float* __restrict__ Wa, const float* __restrict__ Wo,
    const float* __restrict__ bo,
    float* __restrict__ outE, float* __restrict__ outI, float* __restrict__ outEdge)
{
    const int bqid = blockIdx.x;          // b*256 + q
    const int b = bqid >> 8;
    const int tid = threadIdx.x;
    const int wave = tid >> 6, lane = tid & 63;
    const int arow = lane & 15, kgrp = lane >> 4;

    __shared__ __align__(16) __bf16 sX[KV * 256];      // 16KB: X tile, then H tile
    __shared__ __align__(16) float  sS[KV * SP];       // logits -> p; reused at finalize
    __shared__ __align__(16) float  sEdge[KV][68];     // edge-channel staging (8.7KB)
    __shared__ __align__(16) float  sB1[256];
    __shared__ __align__(16) float  sB2[144];
    __shared__ __align__(16) float  sEquiQ[192];
    __shared__ __align__(16) __bf16 sQm[64];
    __shared__ float sF[72];
    __shared__ float sL[72];
    __shared__ float sL2[72];
    __shared__ int   sAdj[KV];

    sB1[tid] = b1[tid];
    if (tid < 144) sB2[tid] = (tid < 136) ? b2[tid] : 0.f;
    if (tid < 192) sEquiQ[tid] = equis[(size_t)bqid * 192 + tid];
    if (tid < 64)  sQm[tid] = (__bf16)qmsg[(size_t)bqid * 64 + tid];

    // per-thread persistent attention state
    float m_run = -1e30f, l_run = 0.f, l2_run = 0.f;
    float accE = 0.f;                       // role (c,d) for tid<192
    float accI = 0.f;                       // role (h,dd) = (tid>>5, tid&31)
    const int c_e = tid >> 6, d_e = tid & 63;
    const int h_i = tid >> 5;
    __syncthreads();

    for (int kt = 0; kt < 8; ++kt) {
        const int k0 = kt * KV;
        const int kb = b * 256 + k0;

        // ---- build X tile: [KV k-rows][qmsg|kmsg|dot|edges] bf16 ----
        #pragma unroll
        for (int it = 0; it < 2; ++it) {
            const int i = tid + it * 256;
            const int r = i >> 4, c4 = (i & 15) << 2;
            *(bf16x4_t*)&sX[swz(r, c4)] = *(const bf16x4_t*)&sQm[c4];
        }
        #pragma unroll
        for (int it = 0; it < 2; ++it) {
            const int i = tid + it * 256;
            const int r = i >> 4, c4 = (i & 15) << 2;
            f32x4_t v = *(const f32x4_t*)&kmsg[(size_t)(kb + r) * 64 + c4];
            *(bf16x4_t*)&sX[swz(r, 64 + c4)] = cvt4(v);
        }
        #pragma unroll
        for (int it = 0; it < 2; ++it) {
            const int i = tid + it * 256;
            const int r = i >> 4, c4 = (i & 15) << 2;
            const float* ek = &equis[(size_t)(kb + r) * 192 + c4];
            f32x4_t e0 = *(const f32x4_t*)(ek);
            f32x4_t e1 = *(const f32x4_t*)(ek + 64);
            f32x4_t e2 = *(const f32x4_t*)(ek + 128);
            f32x4_t q0 = *(const f32x4_t*)&sEquiQ[c4];
            f32x4_t q1 = *(const f32x4_t*)&sEquiQ[64 + c4];
            f32x4_t q2 = *(const f32x4_t*)&sEquiQ[128 + c4];
            f32x4_t d = e0 * q0 + e1 * q1 + e2 * q2;
            *(bf16x4_t*)&sX[swz(r, 128 + c4)] = cvt4(d);
        }
        #pragma unroll
        for (int it = 0; it < 2; ++it) {
            const int i = tid + it * 256;
            const int r = i >> 4, c4 = (i & 15) << 2;
            f32x4_t v = __builtin_nontemporal_load(
                (const f32x4_t*)&edges[((size_t)bqid * 256 + k0 + r) * 64 + c4]);
            *(bf16x4_t*)&sX[swz(r, 192 + c4)] = cvt4(v);
        }
        if (tid < KV) sAdj[tid] = adj[(size_t)bqid * 256 + k0 + tid];
        __syncthreads();                      // (1) X staged

        // ---- GEMM1: H = silu(X @ W1^T + b1), wave owns 64 FF cols ----
        f32x4_t acc1[2][4];
        {
            const f32x4_t z = {0.f, 0.f, 0.f, 0.f};
            #pragma unroll
            for (int rt = 0; rt < 2; ++rt)
                #pragma unroll
                for (int ct = 0; ct < 4; ++ct) acc1[rt][ct] = z;
        }
        #pragma unroll
        for (int ks = 0; ks < 8; ++ks) {
            const int kk = ks * 32 + (kgrp << 3);
            bf16x8_t afr[2], bfr[4];
            #pragma unroll
            for (int rt = 0; rt < 2; ++rt)
                afr[rt] = *(const bf16x8_t*)&sX[swz((rt << 4) + arow, kk)];
            #pragma unroll
            for (int ct = 0; ct < 4; ++ct) {
                const int o = (wave << 6) + (ct << 4) + arow;
                bfr[ct] = *(const bf16x8_t*)&W1bf[(o << 8) + kk];
            }
            #pragma unroll
            for (int rt = 0; rt < 2; ++rt)
                #pragma unroll
                for (int ct = 0; ct < 4; ++ct)
                    acc1[rt][ct] = __builtin_amdgcn_mfma_f32_16x16x32_bf16(
                        afr[rt], bfr[ct], acc1[rt][ct], 0, 0, 0);
        }
        __syncthreads();                      // (2) all waves done reading X
        #pragma unroll
        for (int rt = 0; rt < 2; ++rt)
            #pragma unroll
            for (int ct = 0; ct < 4; ++ct) {
                const int ccol = (wave << 6) + (ct << 4) + arow;
                const float bb = sB1[ccol];
                #pragma unroll
                for (int j = 0; j < 4; ++j) {
                    const int row = (rt << 4) + (kgrp << 2) + j;
                    float x = acc1[rt][ct][j] + bb;
                    float hh = x * (1.0f / (1.0f + __expf(-x)));
                    sX[swz(row, ccol)] = (__bf16)hh;
                }
            }
        __syncthreads();                      // (3) H ready

        // ---- GEMM2: messages = H @ W2^T + b2 (out cols padded 136->144) ----
        const int ct0 = wave ? (2 * wave + 1) : 0;   // 0,3,5,7
        const int nct = wave ? 2 : 3;
        f32x4_t acc2[2][3];
        {
            const f32x4_t z = {0.f, 0.f, 0.f, 0.f};
            #pragma unroll
            for (int rt = 0; rt < 2; ++rt)
                #pragma unroll
                for (int ci = 0; ci < 3; ++ci) acc2[rt][ci] = z;
        }
        #pragma unroll
        for (int ks = 0; ks < 8; ++ks) {
            const int kk = ks * 32 + (kgrp << 3);
            bf16x8_t afr[2], bfr[3];
            #pragma unroll
            for (int rt = 0; rt < 2; ++rt)
                afr[rt] = *(const bf16x8_t*)&sX[swz((rt << 4) + arow, kk)];
            #pragma unroll
            for (int ci = 0; ci < 3; ++ci)
                if (ci < nct) {
                    const int o = ((ct0 + ci) << 4) + arow;
                    bfr[ci] = *(const bf16x8_t*)&W2bf[(o << 8) + kk];
                }
            #pragma unroll
            for (int rt = 0; rt < 2; ++rt)
                #pragma unroll
                for (int ci = 0; ci < 3; ++ci)
                    if (ci < nct)
                        acc2[rt][ci] = __builtin_amdgcn_mfma_f32_16x16x32_bf16(
                            afr[rt], bfr[ci], acc2[rt][ci], 0, 0, 0);
        }
        // epilogue: logits (ch<72) -> sS, edge channels -> sEdge (LDS)
        #pragma unroll
        for (int ci = 0; ci < 3; ++ci)
            if (ci < nct) {
                const int ch = ((ct0 + ci) << 4) + arow;
                const float bb = sB2[ch];
                #pragma unroll
                for (int rt = 0; rt < 2; ++rt)
                    #pragma unroll
                    for (int j = 0; j < 4; ++j) {
                        const int r = (rt << 4) + (kgrp << 2) + j;
                        const float v = acc2[rt][ci][j] + bb;
                        if (ch < 72) sS[r * SP + ch] = v;
                        else if (ch < 136) sEdge[r][ch - 72] = v;
                    }
            }
        __syncthreads();                      // (4) logits + edges + adj ready

        // ---- coalesced edge_out flush (nontemporal, full 256B rows) ----
        #pragma unroll
        for (int it = 0; it < 2; ++it) {
            const int i = tid + it * 256;
            const int r = i >> 4, c4 = (i & 15) << 2;
            f32x4_t v = *(const f32x4_t*)&sEdge[r][c4];
            __builtin_nontemporal_store(
                v, (f32x4_t*)&outEdge[((size_t)bqid * 256 + k0 + r) * 64 + c4]);
        }

        // ---- pass A: per-channel online softmax (masked skip == exact ref) ----
        if (tid < 72) {
            float tm = -1e30f;
            #pragma unroll 8
            for (int k = 0; k < KV; ++k)
                if (sAdj[k]) tm = fmaxf(tm, sS[k * SP + tid]);
            const float mN = fmaxf(m_run, tm);
            const float f = __expf(m_run - mN);
            float s1 = 0.f, s2 = 0.f;
            #pragma unroll 8
            for (int k = 0; k < KV; ++k) {
                float p = sAdj[k] ? __expf(sS[k * SP + tid] - mN) : 0.f;
                sS[k * SP + tid] = p;
                s1 += p; s2 += p * p;
            }
            l_run = l_run * f + s1;
            l2_run = l2_run * f * f + s2;
            m_run = mN;
            sF[tid] = f;
        }
        __syncthreads();                      // (5) p + rescale factors ready

        // ---- pass B: accumulate attention outputs ----
        if (tid < 192) {
            float a = accE * sF[d_e];
            const float* pe = &projE[((size_t)kb * 3 + c_e) * 64 + d_e];
            #pragma unroll 8
            for (int k = 0; k < KV; ++k)
                a += sS[k * SP + d_e] * pe[k * 192];
            accE = a;
        }
        {
            float a = accI * sF[64 + h_i];
            const float* pf = &projF[(size_t)kb * 256 + tid];
            #pragma unroll 8
            for (int k = 0; k < KV; ++k)
                a += sS[k * SP + 64 + h_i] * pf[k * 256];
            accI = a;
        }
        // no barrier needed: next writes to sS/sF occur after >=1 barrier
    }

    // ---- finalize ----
    if (tid < 72) { sL[tid] = l_run; sL2[tid] = l2_run; }
    __syncthreads();                          // fences last pass-B sS reads
    if (tid < 192) {
        const float ll = sL[d_e];
        sS[tid] = accE * sqrtf(sL2[d_e]) / (ll * ll);            // out_e[c][d]
    }
    {
        const float ll = sL[64 + h_i];
        sS[256 + tid] = accI * sqrtf(sL2[64 + h_i]) / (ll * ll); // out_i flat
    }
    __syncthreads();
    if (tid < 192) {                          // equi_updates = out_e @ Wa^T
        const int c = tid >> 6, e = tid & 63;
        float s = 0.f;
        #pragma unroll 8
        for (int d2 = 0; d2 < 64; ++d2) s += sS[c * 64 + d2] * Wa[e * 64 + d2];
        outE[((size_t)bqid * 3 + c) * 64 + e] = s;
    }
    {                                         // inv_updates = out_i @ Wo^T + bo
        float s = 0.f;
        const float* wo = &Wo[tid * 256];
        #pragma unroll 8
        for (int i = 0; i < 256; ++i) s += sS[256 + i] * wo[i];
        outI[(size_t)bqid * 256 + tid] = s + bo[tid];
    }
}

extern "C" void kernel_launch(void* const* d_in, const int* in_sizes, int n_in,
                              void* d_out, int out_size, void* d_ws, size_t ws_size,
                              hipStream_t stream) {
    (void)in_sizes; (void)n_in; (void)out_size; (void)ws_size;
    const float* equis = (const float*)d_in[0];
    const float* invs  = (const float*)d_in[1];
    const float* edges = (const float*)d_in[2];
    const int*   adj   = (const int*)d_in[3];
    const float* Wq = (const float*)d_in[4];
    const float* bq = (const float*)d_in[5];
    const float* Wk = (const float*)d_in[6];
    const float* bk = (const float*)d_in[7];
    const float* W1 = (const float*)d_in[8];
    const float* b1 = (const float*)d_in[9];
    const float* W2 = (const float*)d_in[10];
    const float* b2 = (const float*)d_in[11];
    const float* Wc = (const float*)d_in[12];
    const float* Wa = (const float*)d_in[13];
    const float* Wi = (const float*)d_in[14];
    const float* bi = (const float*)d_in[15];
    const float* Wo = (const float*)d_in[16];
    const float* bo = (const float*)d_in[17];

    float* out = (float*)d_out;
    float* outE    = out;                  // (B,N,3,64)  = 196608
    float* outI    = out + 196608;         // (B,N,256)   = 262144
    float* outEdge = out + 458752;         // (B,N,N,64)  = 16777216

    char* ws = (char*)d_ws;
    __bf16* W1bf = (__bf16*)(ws);                    // 131072 B
    __bf16* W2bf = (__bf16*)(ws + 131072);           //  73728 B
    float* qmsg  = (float*)(ws + 204800);            // 262144 B
    float* kmsg  = (float*)(ws + 466944);            // 262144 B
    float* projE = (float*)(ws + 729088);            // 786432 B
    float* projF = (float*)(ws + 1515520);           // 1048576 B

    semla_pre<<<153, 256, 0, stream>>>(invs, equis, Wq, bq, Wk, bk, Wc, Wi, bi,
                                       W1, W2, W1bf, W2bf, qmsg, kmsg, projE, projF);
    semla_main<<<1024, 256, 0, stream>>>(equis, edges, adj, W1bf, W2bf, qmsg, kmsg,
                                         projE, projF, b1, b2, Wa, Wo, bo,
                                         outE, outI, outEdge);
}